// Round 12
// baseline (21.665 us; speedup 1.0000x reference)
//
#include <hip/hip_runtime.h>

#define TPL_SIZE 16384
#define TPL_K 16
#define TPL_ND 5
#define TPL_BLK 512
#define TPL_PTS 4                                  // points per thread
#define TPL_PAIRS (TPL_PTS / 2)                    // processed as f32x2 pairs
#define TPL_SPAN (TPL_BLK * TPL_PTS)               // 2048 points per block
#define TPL_BPB (TPL_SIZE / TPL_SPAN)              // 8 blocks per batch
#define TPL_NXCD 8

typedef __attribute__((ext_vector_type(2))) float f32x2;

// R10 base (21.1 us) + PAIR-PACKED solve (R12).
// Diagnosis: R10 (rcp, -2.3us) vs R11 (fewer VALU ops, +-0) => the kernel is
// dependency-LATENCY bound at 2 waves/SIMD (128 KB LDS pins 1 block/CU);
// the ~500-cycle serial 5x5 GE chain per point dominates. Fix: solve TWO
// points per traversal with all state in f32x2 halves (v_pk_*_f32) -- same
// chain length, 2 points retired => solve wall-time per point halves.
// - XCD remap: a batch's 8 blocks share blockIdx%8 -> same XCD L2 (R8).
// - 512-thread blocks ((512,2) -> 256-VGPR budget; 1024-thread variants hit
//   a 64-VGPR ceiling and spilled, R5/R6).
// - rcp pivots, reciprocals reused in back-sub (R10).
// - next-pair edge/dist prefetch issued between gather and accumulate
//   phases (bounds peak live regs ~220 < 256; spill tell = WRITE_SIZE).
__global__ __launch_bounds__(TPL_BLK, 2) void tp_lds_kernel(
    const float* __restrict__ x,
    const float* __restrict__ points,
    const int*   __restrict__ edge_index,
    const float* __restrict__ dtp,
    const float* __restrict__ dist,
    const float* __restrict__ weight,
    float* __restrict__ out)
{
    extern __shared__ uint2 lds_pv[];   // [TPL_SIZE] = 128 KB

    const int tid = threadIdx.x;
    const int blk = blockIdx.x;

    // blk -> (batch, chunk): xcd = blk&7 ; 4 batches per XCD
    const int xcd   = blk & (TPL_NXCD - 1);
    const int batch = xcd * 4 + (blk >> 6);          // [0,32)
    const int chunk = (blk >> 3) & (TPL_BPB - 1);    // [0,8)

    const size_t base = (size_t)batch * TPL_SIZE + chunk * TPL_SPAN;

    // ---- issue pair 0's streaming loads FIRST (hide under staging) ----
    int4   ciA[4], ciB[4];
    float4 cwA[4], cwB[4];
    {
        const int4*   eA = reinterpret_cast<const int4*>(edge_index + (base + tid) * TPL_K);
        const float4* dA = reinterpret_cast<const float4*>(dist      + (base + tid) * TPL_K);
        const int4*   eB = reinterpret_cast<const int4*>(edge_index + (base + TPL_BLK + tid) * TPL_K);
        const float4* dB = reinterpret_cast<const float4*>(dist      + (base + TPL_BLK + tid) * TPL_K);
        #pragma unroll
        for (int q = 0; q < 4; ++q) {
            ciA[q] = eA[q]; cwA[q] = dA[q];
            ciB[q] = eB[q]; cwB[q] = dB[q];
        }
    }

    // ---- stage + quantize the whole batch table into LDS (coalesced) ----
    {
        const float4* pb4 = reinterpret_cast<const float4*>(points + (size_t)batch * TPL_SIZE * 2);
        const float2* xb2 = reinterpret_cast<const float2*>(x + (size_t)batch * TPL_SIZE);
        uint4* lds4 = reinterpret_cast<uint4*>(lds_pv);
        #pragma unroll
        for (int k = 0; k < TPL_SIZE / (2 * TPL_BLK); ++k) {   // 16 iters
            int g = k * TPL_BLK + tid;        // pair-group index
            float4 pp = pb4[g];               // points for entries 2g, 2g+1
            float2 xv = xb2[g];               // values for entries 2g, 2g+1
            unsigned ux0 = (unsigned)(pp.x * 65536.0f);
            unsigned uy0 = (unsigned)(pp.y * 65536.0f);
            unsigned ux1 = (unsigned)(pp.z * 65536.0f);
            unsigned uy1 = (unsigned)(pp.w * 65536.0f);
            if (ux0 > 65535u) ux0 = 65535u;
            if (uy0 > 65535u) uy0 = 65535u;
            if (ux1 > 65535u) ux1 = 65535u;
            if (uy1 > 65535u) uy1 = 65535u;
            uint4 wv;
            wv.x = ux0 | (uy0 << 16);
            wv.y = __float_as_uint(xv.x);
            wv.z = ux1 | (uy1 << 16);
            wv.w = __float_as_uint(xv.y);
            lds4[g] = wv;
        }
    }
    __syncthreads();

    const float wt0 = weight[0], wt1 = weight[1], wt2 = weight[2],
                wt3 = weight[3], wt4 = weight[4];
    const float dtv = dtp[0];

    #pragma unroll
    for (int pp = 0; pp < TPL_PAIRS; ++pp) {
        const int    sA   = chunk * TPL_SPAN + (2 * pp) * TPL_BLK + tid;
        const int    sB   = sA + TPL_BLK;
        const size_t rowA = base + (2 * pp) * TPL_BLK + tid;
        const size_t rowB = rowA + TPL_BLK;

        // self points (same quantization as neighbors)
        uint2 seA = lds_pv[sA];
        uint2 seB = lds_pv[sB];
        const int sxA = (int)(seA.x & 0xffffu), syA = (int)(seA.x >> 16);
        const int sxB = (int)(seB.x & 0xffffu), syB = (int)(seB.x >> 16);
        const f32x2 sv2 = {__uint_as_float(seA.y), __uint_as_float(seB.y)};

        // unpack ids / weights (static indices)
        int   idsA[TPL_K], idsB[TPL_K];
        f32x2 wgt2[TPL_K];
        #pragma unroll
        for (int q = 0; q < 4; ++q) {
            idsA[4*q+0] = ciA[q].x; idsA[4*q+1] = ciA[q].y;
            idsA[4*q+2] = ciA[q].z; idsA[4*q+3] = ciA[q].w;
            idsB[4*q+0] = ciB[q].x; idsB[4*q+1] = ciB[q].y;
            idsB[4*q+2] = ciB[q].z; idsB[4*q+3] = ciB[q].w;
            wgt2[4*q+0] = (f32x2){cwA[q].x, cwB[q].x};
            wgt2[4*q+1] = (f32x2){cwA[q].y, cwB[q].y};
            wgt2[4*q+2] = (f32x2){cwA[q].z, cwB[q].z};
            wgt2[4*q+3] = (f32x2){cwA[q].w, cwB[q].w};
        }

        // gather both points' neighbors (32 ds_reads issued together)
        uint2 nA[TPL_K], nB[TPL_K];
        #pragma unroll
        for (int t = 0; t < TPL_K; ++t) {
            nA[t] = lds_pv[idsA[t] & (TPL_SIZE - 1)];
            nB[t] = lds_pv[idsB[t] & (TPL_SIZE - 1)];
        }

        // prefetch next pair's edge/dist (HBM latency hides under
        // accumulate + solve; placed here to bound live registers)
        int4   niA[4], niB[4];
        float4 nwA[4], nwB[4];
        if (pp + 1 < TPL_PAIRS) {
            const size_t rA = base + (2 * (pp + 1)) * TPL_BLK + tid;
            const size_t rB = rA + TPL_BLK;
            const int4*   eA = reinterpret_cast<const int4*>(edge_index + rA * TPL_K);
            const float4* dA = reinterpret_cast<const float4*>(dist      + rA * TPL_K);
            const int4*   eB = reinterpret_cast<const int4*>(edge_index + rB * TPL_K);
            const float4* dB = reinterpret_cast<const float4*>(dist      + rB * TPL_K);
            #pragma unroll
            for (int q = 0; q < 4; ++q) {
                niA[q] = eA[q]; nwA[q] = dA[q];
                niB[q] = eB[q]; nwB[q] = dB[q];
            }
        }

        // ---- packed accumulation: lane-vector halves = {point A, point B} ----
        f32x2 ata2[15], atb2[TPL_ND];
        #pragma unroll
        for (int i = 0; i < 15; ++i) ata2[i] = (f32x2)0.0f;
        #pragma unroll
        for (int i = 0; i < TPL_ND; ++i) atb2[i] = (f32x2)0.0f;

        #pragma unroll
        for (int t = 0; t < TPL_K; ++t) {
            int dxiA = (int)(nA[t].x & 0xffffu) - sxA;
            int dyiA = (int)(nA[t].x >> 16)     - syA;
            int dxiB = (int)(nB[t].x & 0xffffu) - sxB;
            int dyiB = (int)(nB[t].x >> 16)     - syB;
            f32x2 dx = (f32x2){(float)dxiA, (float)dxiB} * 0x1p-16f;
            f32x2 dy = (f32x2){(float)dyiA, (float)dyiB} * 0x1p-16f;
            f32x2 w  = wgt2[t];
            f32x2 nv = {__uint_as_float(nA[t].y), __uint_as_float(nB[t].y)};
            f32x2 hw = w * 0.5f;
            f32x2 a[TPL_ND];
            a[0] = dx * w;
            a[1] = dy * w;
            a[2] = dx * dx * hw;
            a[3] = dx * dy * w;
            a[4] = dy * dy * hw;
            f32x2 bwv = (nv - sv2) * w;
            int c = 0;
            #pragma unroll
            for (int i = 0; i < TPL_ND; ++i) {
                #pragma unroll
                for (int j = i; j < TPL_ND; ++j) { ata2[c] += a[i] * a[j]; ++c; }
                atb2[i] += a[i] * bwv;
            }
        }

        // ---- PAIR-PACKED 5x5 SPD solve: one GE traversal, two points ----
        f32x2 M2[TPL_ND][TPL_ND], r2[TPL_ND], pinv2[TPL_ND];
        {
            int c = 0;
            #pragma unroll
            for (int i = 0; i < TPL_ND; ++i) {
                #pragma unroll
                for (int j = i; j < TPL_ND; ++j) { M2[i][j] = ata2[c]; M2[j][i] = ata2[c]; ++c; }
                r2[i] = atb2[i];
                M2[i][i] += 1e-6f;
            }
        }
        #pragma unroll
        for (int i = 0; i < TPL_ND; ++i) {
            f32x2 inv2 = {__builtin_amdgcn_rcpf(M2[i][i].x),
                          __builtin_amdgcn_rcpf(M2[i][i].y)};
            pinv2[i] = inv2;
            #pragma unroll
            for (int j = i + 1; j < TPL_ND; ++j) {
                f32x2 f = M2[j][i] * inv2;
                #pragma unroll
                for (int cc = i + 1; cc < TPL_ND; ++cc) M2[j][cc] -= f * M2[i][cc];
                r2[j] -= f * r2[i];
            }
        }
        f32x2 sol2[TPL_ND];
        #pragma unroll
        for (int i = TPL_ND - 1; i >= 0; --i) {
            f32x2 acc = r2[i];
            #pragma unroll
            for (int cc = i + 1; cc < TPL_ND; ++cc) acc -= M2[i][cc] * sol2[cc];
            sol2[i] = acc * pinv2[i];
        }

        f32x2 du2 = sol2[0] * wt0 + sol2[1] * wt1 + sol2[2] * wt2
                  + sol2[3] * wt3 + sol2[4] * wt4;
        out[rowA] = sv2.x + dtv * du2.x;
        out[rowB] = sv2.y + dtv * du2.y;

        // rotate pipeline (static indices only)
        if (pp + 1 < TPL_PAIRS) {
            #pragma unroll
            for (int q = 0; q < 4; ++q) {
                ciA[q] = niA[q]; cwA[q] = nwA[q];
                ciB[q] = niB[q]; cwB[q] = nwB[q];
            }
        }
    }
}

extern "C" void kernel_launch(void* const* d_in, const int* in_sizes, int n_in,
                              void* d_out, int out_size, void* d_ws, size_t ws_size,
                              hipStream_t stream) {
    const float* x          = (const float*)d_in[0];
    const float* points     = (const float*)d_in[1];
    const int*   edge_index = (const int*)d_in[2];
    const float* dtp        = (const float*)d_in[3];
    const float* dist       = (const float*)d_in[4];
    const float* weight     = (const float*)d_in[5];
    float* out = (float*)d_out;

    int total = out_size;                    // B * SIZE = 524288
    int grid  = total / TPL_SPAN;            // 256 blocks (8 per batch)
    size_t lds_bytes = (size_t)TPL_SIZE * sizeof(uint2);  // 128 KB

    tp_lds_kernel<<<grid, TPL_BLK, lds_bytes, stream>>>(
        x, points, edge_index, dtp, dist, weight, out);
}